// Round 17
// baseline (338.403 us; speedup 1.0000x reference)
//
#include <hip/hip_runtime.h>

#define NN 50000
#define NE 400000
#define DIN 32
#define DH  128
#define DOUT 16
#define NB  2
#define NBLK 49          // ceil(NN/1024)
#define NTILE (NE / 64)  // 6250
#define TPW   5          // 16-edge tiles per wave (contiguous, fully unrolled)
#define NWG_E (NE / 320) // 1250 wgs x 4 waves x 80 contiguous edges

typedef _Float16 half8 __attribute__((ext_vector_type(8)));
typedef _Float16 half4 __attribute__((ext_vector_type(4)));
typedef float    f32x4 __attribute__((ext_vector_type(4)));

#define FENCE() asm volatile("s_waitcnt lgkmcnt(0)" ::: "memory")
#define MFMA16(a, b, c) __builtin_amdgcn_mfma_f32_16x16x32_f16((a), (b), (c), 0, 0, 0)

// ---------------------------------------------------------------------------
// Mega-prep kernel: weight fragments + dst histogram (round 11/12, verified).
__global__ void k_prep(const float* __restrict__ w1a, const float* __restrict__ w1b,
                       const float* __restrict__ w1c, const float* __restrict__ w2a,
                       const float* __restrict__ w2b, const float* __restrict__ wout,
                       const float* __restrict__ win, const int* __restrict__ dstI,
                       _Float16* __restrict__ wf, int* __restrict__ deg) {
    const int b = blockIdx.x, tid = threadIdx.x;
    if (b < (NB * 12288) / 256) {               // ---- block-weight frags
        int c = b * 256 + tid;
        int bb = c / 12288, r = c % 12288;
        int tt = r >> 9, rem = r & 511;
        const float* W; int t;
        if (tt < 8)       { W = w1a + (size_t)bb * 2 * DH * DH; t = tt; }
        else if (tt < 12) { W = w1b + (size_t)bb * DH * DH; t = tt - 8; }
        else if (tt < 16) { W = w1c + (size_t)bb * DH * DH; t = tt - 12; }
        else if (tt < 20) { W = w2a + (size_t)bb * DH * DH; t = tt - 16; }
        else              { W = w2b + (size_t)bb * DH * DH; t = tt - 20; }
        bool perm = (tt >= 12 && tt < 16);      // w1c only (in-lane phi)
        int n = rem >> 6, l = rem & 63;
        int col = n * 16 + (l & 15);
        half8 v;
#pragma unroll
        for (int j = 0; j < 8; ++j) {
            int row = perm ? ((2 * t + (j >> 2)) * 16 + (l >> 4) * 4 + (j & 3))
                           : (t * 32 + (l >> 4) * 8 + j);
            v[j] = (_Float16)W[(size_t)row * DH + col];
        }
        *(half8*)(wf + (size_t)c * 8) = v;
    } else if (b == 96) {                       // ---- wout frags (256 chunks)
        int c = tid;
        int t = c >> 6, l = c & 63;
        half8 v;
#pragma unroll
        for (int j = 0; j < 8; ++j)
            v[j] = (_Float16)wout[(size_t)(t * 32 + (l >> 4) * 8 + j) * DOUT + (l & 15)];
        *(half8*)(wf + (size_t)(NB * 12288 + c) * 8) = v;
    } else if (b < 99) {                        // ---- win frags (512 chunks, K=32)
        int c = (b - 97) * 256 + tid;
        int n = c >> 6, l = c & 63;
        half8 v;
#pragma unroll
        for (int j = 0; j < 8; ++j)
            v[j] = (_Float16)win[(size_t)((l >> 4) * 8 + j) * DH + n * 16 + (l & 15)];
        *(half8*)(wf + (size_t)(NB * 12288 + 256 + c) * 8) = v;
    } else {                                    // ---- dst histogram
        int e = (b - 99) * 256 + tid;
        if (e < NE) atomicAdd(&deg[dstI[e]], 1);
    }
}

// ---------------------------------------------------------------------------
// CSR sort by dst: 3-phase scan -> scatter
__global__ void __launch_bounds__(1024) k_scanA(const int* __restrict__ deg,
                                                int* __restrict__ bsum) {
    __shared__ int ws[16];
    int tid = threadIdx.x, wv = tid >> 6, l = tid & 63;
    int i = blockIdx.x * 1024 + tid;
    int v = (i < NN) ? deg[i] : 0;
#pragma unroll
    for (int off = 32; off; off >>= 1) v += __shfl_down(v, off);
    if (l == 0) ws[wv] = v;
    __syncthreads();
    if (tid == 0) {
        int s = 0;
#pragma unroll
        for (int k = 0; k < 16; ++k) s += ws[k];
        bsum[blockIdx.x] = s;
    }
}

__global__ void k_scanB(const int* __restrict__ bsum, int* __restrict__ boff) {
    int l = threadIdx.x;  // 64 threads
    int v = (l < NBLK) ? bsum[l] : 0;
    int s = v;
#pragma unroll
    for (int off = 1; off < 64; off <<= 1) {
        int t = __shfl_up(s, off);
        if (l >= off) s += t;
    }
    if (l < NBLK) boff[l] = s - v;
}

__global__ void __launch_bounds__(1024) k_scanC(const int* __restrict__ deg,
                                                const int* __restrict__ boff,
                                                int* __restrict__ cur) {
    __shared__ int ws[16];
    int tid = threadIdx.x, wv = tid >> 6, l = tid & 63;
    int i = blockIdx.x * 1024 + tid;
    int v = (i < NN) ? deg[i] : 0;
    int s = v;
#pragma unroll
    for (int off = 1; off < 64; off <<= 1) {
        int t = __shfl_up(s, off);
        if (l >= off) s += t;
    }
    if (l == 63) ws[wv] = s;
    __syncthreads();
    if (wv == 0) {
        int t = (l < 16) ? ws[l] : 0;
#pragma unroll
        for (int off = 1; off < 16; off <<= 1) {
            int u = __shfl_up(t, off);
            if (l >= off) t += u;
        }
        if (l < 16) ws[l] = t;
    }
    __syncthreads();
    int base = boff[blockIdx.x] + (wv ? ws[wv - 1] : 0);
    if (i < NN) cur[i] = base + s - v;
}

__global__ void k_scatter(const int* __restrict__ srcI, const int* __restrict__ dstI,
                          int* __restrict__ cur, int* __restrict__ eS,
                          int* __restrict__ eD) {
    int e = blockIdx.x * blockDim.x + threadIdx.x;
    if (e >= NE) return;
    int d = dstI[e];
    int p = atomicAdd(&cur[d], 1);
    eS[p] = srcI[e];
    eD[p] = d;
}

// ---------------------------------------------------------------------------
// Fused input proj + y precompute (block 0) + agg zeroing (round 12, verified)
__global__ void __launch_bounds__(256, 4) k_y0(
    const float* __restrict__ inp,
    const half8* __restrict__ winf, const float* __restrict__ bin,
    const half8* __restrict__ wfa, const float* __restrict__ b1a,
    _Float16* __restrict__ yj, _Float16* __restrict__ yi,
    float* __restrict__ agg) {
    __shared__ _Float16 sM[4][2048];
    const int tid = threadIdx.x, wv = tid >> 6, l = tid & 63;
    const int lm = l & 15, lk = l >> 4;
    const int n0 = (blockIdx.x * 4 + wv) * 16;
    if (n0 >= NN) return;
    int node = n0 + lm;
    if (node >= NN) node = NN - 1;

    {
        float4 z4 = make_float4(0.f, 0.f, 0.f, 0.f);
#pragma unroll
        for (int r = 0; r < 4; ++r) {
            int nd = n0 + lk * 4 + r;
            if (nd < NN) {
                float4* q = (float4*)(agg + (size_t)nd * DH + lm * 8);
                q[0] = z4; q[1] = z4;
            }
        }
    }

    const f32x4 z = {0.f, 0.f, 0.f, 0.f};
    half8 a0;
    {
        const float* ip = inp + (size_t)node * DIN + lk * 8;
        float4 v0 = *(const float4*)ip;
        float4 v1 = *(const float4*)(ip + 4);
#pragma unroll
        for (int j = 0; j < 4; ++j) {
            a0[j]     = (_Float16)(&v0.x)[j];
            a0[4 + j] = (_Float16)(&v1.x)[j];
        }
    }
    f32x4 xacc[8];
#pragma unroll
    for (int n = 0; n < 8; ++n) xacc[n] = z;
#pragma unroll
    for (int n = 0; n < 8; ++n) xacc[n] = MFMA16(a0, winf[n * 64 + l], xacc[n]);

    _Float16* sm = sM[wv];
#pragma unroll
    for (int n = 0; n < 8; ++n) {
        float bi = bin[n * 16 + lm];
        int base = ((n >> 1) * 64 + ((n & 1) * 2 + (lm >> 3)) * 16 + lk * 4) * 8 +
                   (lm & 7);
#pragma unroll
        for (int j = 0; j < 4; ++j)
            sm[base + j * 8] = (_Float16)(xacc[n][j] + bi);
    }
    FENCE();

    f32x4 aj[8], ai[8];
#pragma unroll
    for (int n = 0; n < 8; ++n) { aj[n] = z; ai[n] = z; }
#pragma unroll
    for (int t = 0; t < 4; ++t) {
        half8 a = *(const half8*)&sm[(t * 64 + l) * 8];
#pragma unroll
        for (int n = 0; n < 8; ++n) {
            aj[n] = MFMA16(a, wfa[(size_t)(t * 8 + n) * 64 + l], aj[n]);
            ai[n] = MFMA16(a, wfa[(size_t)((t + 4) * 8 + n) * 64 + l], ai[n]);
        }
    }
#pragma unroll
    for (int n = 0; n < 8; ++n) {
        float bi = b1a[n * 16 + lm];
#pragma unroll
        for (int r = 0; r < 4; ++r) {
            int nd = n0 + lk * 4 + r;
            if (nd < NN) {
                yj[(size_t)nd * DH + n * 16 + lm] = (_Float16)aj[n][r];
                yi[(size_t)nd * DH + n * 16 + lm] = (_Float16)(ai[n][r] + bi);
            }
        }
    }
}

// ---------------------------------------------------------------------------
// Edge MLP v17: cross-tile-carry segment-sum on CONTIGUOUS per-wave edges.
// Wave wv owns edges [wg*320 + wv*80, +80) as 5 contiguous 16-edge tiles, so
// the previous tile's last edge is the global predecessor of this tile's
// first edge: merge test exact, interior runs provably single-writer (plain
// stores), chain endpoints (slot0-when-carry_first / final carry) atomic.
// Round-16's bug: tiles were strided 64, so runs flowed into OTHER waves.
__global__ void __launch_bounds__(256, 2) k_edge12(
    const _Float16* __restrict__ yj, const _Float16* __restrict__ yi,
    const int* __restrict__ eS, const int* __restrict__ eD,
    const half8* __restrict__ wfb, const half8* __restrict__ wfc,
    const float* __restrict__ b1b,
    float* __restrict__ agg) {
    __shared__ _Float16 smAll[4][4096];   // 8KB/wave segsum B-region
    __shared__ int slotT[4][16];

    const int tid = threadIdx.x, wv = tid >> 6, l = tid & 63;
    const int lm = l & 15, lk = l >> 4;

    // bijective XCD-chunked wg swizzle (NWG_E=1250: q=156, r=2)
    int bid = blockIdx.x;
    int xcd = bid & 7, idx = bid >> 3;
    int wg = (xcd < 2 ? xcd * 157 : 2 * 157 + (xcd - 2) * 156) + idx;
    const int ebase0 = wg * 320 + wv * 80;   // CONTIGUOUS 80 edges per wave

    _Float16* sm = smAll[wv];
    if (lk >= 2) {   // zero B k-slots 16..31 once
        half8 zz;
#pragma unroll
        for (int j = 0; j < 8; ++j) zz[j] = (_Float16)0.f;
#pragma unroll
        for (int g = 0; g < 8; ++g) *(half8*)&sm[(g * 64 + l) * 8] = zz;
    }

    half4 bb[8];
#pragma unroll
    for (int n = 0; n < 8; ++n) {
        float4 bf = *(const float4*)(b1b + n * 16 + lk * 4);
#pragma unroll
        for (int r = 0; r < 4; ++r) bb[n][r] = (_Float16)(&bf.x)[r];
    }

    const f32x4 z = {0.f, 0.f, 0.f, 0.f};

    // carry state (run possibly continuing into next tile)
    float c8[8];
#pragma unroll
    for (int g = 0; g < 8; ++g) c8[g] = 0.f;
    int carry_dst = -1;
    bool carry_first = false;

    // ---- pipeline prologue: tile 0 ids + gathers
    int src = eS[ebase0 + lm];
    int dst = eD[ebase0 + lm];
    half8 ya0, ya1, ya2, ya3, yb0, yb1, yb2, yb3;
    ya0 = *(const half8*)(yj + (size_t)src * DH + 0 * 32 + lk * 8);
    ya1 = *(const half8*)(yj + (size_t)src * DH + 1 * 32 + lk * 8);
    ya2 = *(const half8*)(yj + (size_t)src * DH + 2 * 32 + lk * 8);
    ya3 = *(const half8*)(yj + (size_t)src * DH + 3 * 32 + lk * 8);
    yb0 = *(const half8*)(yi + (size_t)dst * DH + 0 * 32 + lk * 8);
    yb1 = *(const half8*)(yi + (size_t)dst * DH + 1 * 32 + lk * 8);
    yb2 = *(const half8*)(yi + (size_t)dst * DH + 2 * 32 + lk * 8);
    yb3 = *(const half8*)(yi + (size_t)dst * DH + 3 * 32 + lk * 8);

#pragma unroll
    for (int i = 0; i < TPW; ++i) {            // compile-time i (full unroll)
        const int ebase = ebase0 + i * 16;     // contiguous tiles

        // prefetch next tile's edge ids (static condition)
        int srcN = 0, dstN = 0;
        if (i + 1 < TPW) {
            srcN = eS[ebase + 16 + lm];
            dstN = eD[ebase + 16 + lm];
        }

        // run/slot machinery over this tile's 16 sorted dsts
        int slot0dst = __shfl(dst, 0);          // wave-uniform
        int dprev = __shfl(dst, (l & 48) | ((lm - 1) & 15));
        bool bit = (lm == 0) || (dst != dprev);
        unsigned mask16 = (unsigned)__ballot(bit) & 0xFFFFu;
        int slot_l = __popc(mask16 & ((2u << lm) - 1)) - 1;
        int nsl = __popc(mask16);
        if (l < 16 && bit) slotT[wv][slot_l] = dst;

        // carry merge decision + flush of non-continuing carry
        const bool merge = (i > 0) && (slot0dst == carry_dst);
        if (i > 0 && !merge) {
            float* ap = agg + (size_t)carry_dst * DH + lm;
            if (lk == 0) {
                if (carry_first) {
#pragma unroll
                    for (int g = 0; g < 8; ++g)
                        unsafeAtomicAdd(ap + g * 16, c8[g]);
                } else {
#pragma unroll
                    for (int g = 0; g < 8; ++g) ap[g * 16] = c8[g];
                }
            }
        }

        // ---- layer 2: K=128, B = relu(yj+yi) (consumes ya*/yb*)
        f32x4 acc[8];
#pragma unroll
        for (int n = 0; n < 8; ++n) acc[n] = z;
        {
            half8 m1;
#pragma unroll
            for (int j = 0; j < 8; ++j) {
                _Float16 v = ya0[j] + yb0[j];
                m1[j] = v > (_Float16)0.f ? v : (_Float16)0.f;
            }
#pragma unroll
            for (int n = 0; n < 8; ++n)
                acc[n] = MFMA16(wfb[(size_t)(0 * 8 + n) * 64 + l], m1, acc[n]);
#pragma unroll
            for (int j = 0; j < 8; ++j) {
                _Float16 v = ya1[j] + yb1[j];
                m1[j] = v > (_Float16)0.f ? v : (_Float16)0.f;
            }
#pragma unroll
            for (int n = 0; n < 8; ++n)
                acc[n] = MFMA16(wfb[(size_t)(1 * 8 + n) * 64 + l], m1, acc[n]);
#pragma unroll
            for (int j = 0; j < 8; ++j) {
                _Float16 v = ya2[j] + yb2[j];
                m1[j] = v > (_Float16)0.f ? v : (_Float16)0.f;
            }
#pragma unroll
            for (int n = 0; n < 8; ++n)
                acc[n] = MFMA16(wfb[(size_t)(2 * 8 + n) * 64 + l], m1, acc[n]);
#pragma unroll
            for (int j = 0; j < 8; ++j) {
                _Float16 v = ya3[j] + yb3[j];
                m1[j] = v > (_Float16)0.f ? v : (_Float16)0.f;
            }
#pragma unroll
            for (int n = 0; n < 8; ++n)
                acc[n] = MFMA16(wfb[(size_t)(3 * 8 + n) * 64 + l], m1, acc[n]);
        }

        // ---- re-issue gathers for next tile into the now-dead ya*/yb*
        if (i + 1 < TPW) {
            ya0 = *(const half8*)(yj + (size_t)srcN * DH + 0 * 32 + lk * 8);
            ya1 = *(const half8*)(yj + (size_t)srcN * DH + 1 * 32 + lk * 8);
            ya2 = *(const half8*)(yj + (size_t)srcN * DH + 2 * 32 + lk * 8);
            ya3 = *(const half8*)(yj + (size_t)srcN * DH + 3 * 32 + lk * 8);
            yb0 = *(const half8*)(yi + (size_t)dstN * DH + 0 * 32 + lk * 8);
            yb1 = *(const half8*)(yi + (size_t)dstN * DH + 1 * 32 + lk * 8);
            yb2 = *(const half8*)(yi + (size_t)dstN * DH + 2 * 32 + lk * 8);
            yb3 = *(const half8*)(yi + (size_t)dstN * DH + 3 * 32 + lk * 8);
        }

        // ---- layer 3: K=128, B built in-lane via phi from layer-2 acc
        f32x4 ac3[8];
#pragma unroll
        for (int n = 0; n < 8; ++n) ac3[n] = z;
#pragma unroll
        for (int t = 0; t < 4; ++t) {
            half8 b3;
#pragma unroll
            for (int j = 0; j < 8; ++j) {
                int n2 = 2 * t + (j >> 2), r = j & 3;
                float v = acc[n2][r] + (float)bb[n2][r];
                b3[j] = (_Float16)fmaxf(v, 0.f);
            }
#pragma unroll
            for (int n = 0; n < 8; ++n)
                ac3[n] = MFMA16(wfc[(size_t)(t * 8 + n) * 64 + l], b3, ac3[n]);
        }

        // ---- m3 -> segsum B-layout (wave-private)
#pragma unroll
        for (int n = 0; n < 8; ++n)
#pragma unroll
            for (int r = 0; r < 4; ++r)
                sm[(n * 64 + (lm >> 3) * 16 + lk * 4 + r) * 8 + (lm & 7)] =
                    (_Float16)ac3[n][r];
        FENCE();   // covers sm + slotT writes (wave-private)

        // ---- MFMA segment-sum (C seeded with carry) + store/atomic flush
        half8 ind;
#pragma unroll
        for (int e8 = 0; e8 < 8; ++e8) {
            int ks = lk * 8 + e8;
            int se = __shfl(slot_l, ks & 15);
            ind[e8] = (ks < 16 && se == lm) ? (_Float16)1.f : (_Float16)0.f;
        }
        int4 dv = *(const int4*)&slotT[wv][lk * 4];
        const int lkLast = (nsl - 1) >> 2, rLast = (nsl - 1) & 3;
        const int newCarryDst = slotT[wv][nsl - 1];
        const bool slot0_atomic = (i == 0) || (merge && carry_first);
        float c8n[8];
#pragma unroll
        for (int g = 0; g < 8; ++g) {
            half8 bfr = *(const half8*)&sm[(g * 64 + l) * 8];
            f32x4 cseed = z;
            if (merge && lk == 0) cseed[0] = c8[g];
            f32x4 p = MFMA16(ind, bfr, cseed);
#pragma unroll
            for (int r = 0; r < 4; ++r) {
                int s0 = lk * 4 + r;
                if (s0 < nsl - 1) {
                    float* ap = agg + (size_t)(&dv.x)[r] * DH + g * 16 + lm;
                    if (s0 == 0 && slot0_atomic) unsafeAtomicAdd(ap, p[r]);
                    else *ap = p[r];
                }
            }
            float cand = (lk == lkLast)
                ? (rLast == 0 ? p[0] : rLast == 1 ? p[1] : rLast == 2 ? p[2] : p[3])
                : 0.f;
            c8n[g] = __shfl(cand, lkLast * 16 + lm);
        }
#pragma unroll
        for (int g = 0; g < 8; ++g) c8[g] = c8n[g];
        carry_dst = newCarryDst;
        carry_first = (i == 0) ? (nsl == 1)
                               : (merge && (nsl == 1) && carry_first);

        src = srcN; dst = dstN;
    }

    // ---- final carry: may span into the next wave's range -> atomic
    {
        float* ap = agg + (size_t)carry_dst * DH + lm;
        if (lk == 0) {
#pragma unroll
            for (int g = 0; g < 8; ++g) unsafeAtomicAdd(ap + g * 16, c8[g]);
        }
    }
}

// ---------------------------------------------------------------------------
// Node MLP (round 11/12, verified): x = relu((agg + deg*b1c)@w2a + b2a)@w2b + b2b.
template <int MODE>
__global__ void __launch_bounds__(256, 3) k_node10(
    float* __restrict__ agg, const int* __restrict__ deg,
    const float* __restrict__ b1c,
    const half8* __restrict__ w2af, const half8* __restrict__ w2bf,
    const float* __restrict__ b2a, const float* __restrict__ b2b,
    const half8* __restrict__ wfaN, const float* __restrict__ b1aN,
    _Float16* __restrict__ yj, _Float16* __restrict__ yi,
    const half8* __restrict__ woutf, const float* __restrict__ bout,
    float* __restrict__ out) {
    __shared__ _Float16 sM[4][2048];
    const int tid = threadIdx.x, wv = tid >> 6, l = tid & 63;
    const int lm = l & 15, lk = l >> 4;
    const int n0 = (blockIdx.x * 4 + wv) * 16;
    if (n0 >= NN) return;
    int nodeA = n0 + lm;
    if (nodeA >= NN) nodeA = NN - 1;
    const float degf = (float)deg[nodeA];

    float b2ar[8], b2br[8];
#pragma unroll
    for (int n = 0; n < 8; ++n) {
        b2ar[n] = b2a[n * 16 + lm];
        b2br[n] = b2b[n * 16 + lm];
    }

    const f32x4 z = {0.f, 0.f, 0.f, 0.f};
    f32x4 acc[8];
#pragma unroll
    for (int n = 0; n < 8; ++n) acc[n] = z;

    for (int t = 0; t < 4; ++t) {
        float* ap = agg + (size_t)nodeA * DH + t * 32 + lk * 8;
        float4 v0 = *(const float4*)ap;
        float4 v1 = *(const float4*)(ap + 4);
        if (MODE == 0) {   // re-zero for next block (row exclusively owned)
            float4 z4 = make_float4(0.f, 0.f, 0.f, 0.f);
            *(float4*)ap = z4;
            *(float4*)(ap + 4) = z4;
        }
        float4 c0 = *(const float4*)(b1c + t * 32 + lk * 8);
        float4 c1 = *(const float4*)(b1c + t * 32 + lk * 8 + 4);
        half8 a;
#pragma unroll
        for (int j = 0; j < 4; ++j) {
            a[j]     = (_Float16)((&v0.x)[j] + degf * (&c0.x)[j]);
            a[4 + j] = (_Float16)((&v1.x)[j] + degf * (&c1.x)[j]);
        }
        const half8* wp = w2af + (size_t)t * 512 + l;
#pragma unroll
        for (int n = 0; n < 8; ++n) acc[n] = MFMA16(a, wp[n * 64], acc[n]);
    }
    _Float16* sm = sM[wv];
#pragma unroll
    for (int n = 0; n < 8; ++n) {
        int base = ((n >> 1) * 64 + ((n & 1) * 2 + (lm >> 3)) * 16 + lk * 4) * 8 +
                   (lm & 7);
#pragma unroll
        for (int j = 0; j < 4; ++j)
            sm[base + j * 8] = (_Float16)fmaxf(acc[n][j] + b2ar[n], 0.f);
    }
    FENCE();
#pragma unroll
    for (int n = 0; n < 8; ++n) acc[n] = z;
    for (int t = 0; t < 4; ++t) {
        half8 a = *(const half8*)&sm[(t * 64 + l) * 8];
        const half8* wp = w2bf + (size_t)t * 512 + l;
#pragma unroll
        for (int n = 0; n < 8; ++n) acc[n] = MFMA16(a, wp[n * 64], acc[n]);
    }
    FENCE();   // prior frag reads complete before overwrite
#pragma unroll
    for (int n = 0; n < 8; ++n) {
        int base = ((n >> 1) * 64 + ((n & 1) * 2 + (lm >> 3)) * 16 + lk * 4) * 8 +
                   (lm & 7);
#pragma unroll
        for (int j = 0; j < 4; ++j)
            sm[base + j * 8] = (_Float16)(acc[n][j] + b2br[n]);
    }
    FENCE();

    if (MODE == 0) {
        f32x4 aj[8], ai[8];
#pragma unroll
        for (int n = 0; n < 8; ++n) { aj[n] = z; ai[n] = z; }
#pragma unroll
        for (int t = 0; t < 4; ++t) {
            half8 a = *(const half8*)&sm[(t * 64 + l) * 8];
#pragma unroll
            for (int n = 0; n < 8; ++n) {
                aj[n] = MFMA16(a, wfaN[(size_t)(t * 8 + n) * 64 + l], aj[n]);
                ai[n] = MFMA16(a, wfaN[(size_t)((t + 4) * 8 + n) * 64 + l], ai[n]);
            }
        }
#pragma unroll
        for (int n = 0; n < 8; ++n) {
            float bi = b1aN[n * 16 + lm];
#pragma unroll
            for (int r = 0; r < 4; ++r) {
                int nd = n0 + lk * 4 + r;
                if (nd < NN) {
                    yj[(size_t)nd * DH + n * 16 + lm] = (_Float16)aj[n][r];
                    yi[(size_t)nd * DH + n * 16 + lm] = (_Float16)(ai[n][r] + bi);
                }
            }
        }
    } else {
        f32x4 ao = z;
        for (int t = 0; t < 4; ++t) {
            half8 a = *(const half8*)&sm[(t * 64 + l) * 8];
            ao = MFMA16(a, woutf[t * 64 + l], ao);
        }
        float bo = bout[lm];
#pragma unroll
        for (int j = 0; j < 4; ++j) {
            int nd = n0 + lk * 4 + j;
            if (nd < NN) out[(size_t)nd * DOUT + lm] = ao[j] + bo;
        }
    }
}

// ---------------------------------------------------------------------------
extern "C" void kernel_launch(void* const* d_in, const int* in_sizes, int n_in,
                              void* d_out, int out_size, void* d_ws, size_t ws_size,
                              hipStream_t stream) {
    const float* inputs = (const float*)d_in[0];
    const int* eidx = (const int*)d_in[2];
    const int* srcI = eidx;
    const int* dstI = eidx + NE;
    const float* win  = (const float*)d_in[3];
    const float* bin_ = (const float*)d_in[4];
    const float* wout = (const float*)d_in[5];
    const float* bout = (const float*)d_in[6];
    const float* w1a = (const float*)d_in[7];
    const float* b1a = (const float*)d_in[8];
    const float* w1b = (const float*)d_in[9];
    const float* b1b = (const float*)d_in[10];
    const float* w1c = (const float*)d_in[11];
    const float* b1c = (const float*)d_in[12];
    const float* w2a = (const float*)d_in[13];
    const float* b2a = (const float*)d_in[14];
    const float* w2b = (const float*)d_in[15];
    const float* b2b = (const float*)d_in[16];

    char* p = (char*)d_ws;
    _Float16* yj = (_Float16*)p;    p += (size_t)NN * DH * 2;              // 12.8MB
    _Float16* yi = (_Float16*)p;    p += (size_t)NN * DH * 2;              // 12.8MB
    _Float16* wfAll = (_Float16*)p; p += ((size_t)NB * 12288 + 768) * 16;  // 405KB
    float* agg   = (float*)p;       p += (size_t)NN * DH * 4;              // 25.6MB
    int* deg     = (int*)p;         p += (size_t)NN * 4;
    int* cur     = (int*)p;         p += (size_t)NN * 4;
    int* bsum    = (int*)p;         p += 256;
    int* boff    = (int*)p;         p += 256;
    int* eSrt    = (int*)p;         p += (size_t)NE * 4;
    int* eDrt    = (int*)p;         p += (size_t)NE * 4;
    float* out   = (float*)d_out;

    const half8* wb0 = (const half8*)wfAll;
    const half8* wb1 = (const half8*)(wfAll + (size_t)12288 * 8);
    const half8* wfW = (const half8*)(wfAll + (size_t)NB * 12288 * 8);        // wout
    const half8* wfI = (const half8*)(wfAll + (size_t)(NB * 12288 + 256) * 8); // win

    hipMemsetAsync(deg, 0, (size_t)NN * 4, stream);
    k_prep<<<99 + (NE + 255) / 256, 256, 0, stream>>>(
        w1a, w1b, w1c, w2a, w2b, wout, win, dstI, wfAll, deg);
    k_scanA<<<NBLK, 1024, 0, stream>>>(deg, bsum);
    k_scanB<<<1, 64, 0, stream>>>(bsum, boff);
    k_scanC<<<NBLK, 1024, 0, stream>>>(deg, boff, cur);
    k_scatter<<<(NE + 255) / 256, 256, 0, stream>>>(srcI, dstI, cur, eSrt, eDrt);

    const int NWGN = (NN + 63) / 64;
    // block 0 (agg zeroed inside k_y0)
    k_y0<<<NWGN, 256, 0, stream>>>(inputs, wfI, bin_, wb0, b1a, yj, yi, agg);
    k_edge12<<<NWG_E, 256, 0, stream>>>(yj, yi, eSrt, eDrt,
                                        wb0 + 4096, wb0 + 6144, b1b, agg);
    k_node10<0><<<NWGN, 256, 0, stream>>>(
        agg, deg, b1c, wb0 + 8192, wb0 + 10240, b2a, b2b,
        wb1, b1a + DH, yj, yi, nullptr, nullptr, nullptr);
    // block 1 (agg re-zeroed by k_node10<0>)
    k_edge12<<<NWG_E, 256, 0, stream>>>(yj, yi, eSrt, eDrt,
                                        wb1 + 4096, wb1 + 6144, b1b + DH, agg);
    k_node10<1><<<NWGN, 256, 0, stream>>>(
        agg, deg, b1c + DH, wb1 + 8192, wb1 + 10240, b2a + DH, b2b + DH,
        nullptr, nullptr, nullptr, nullptr, wfW, bout, out);
}

// Round 18
// 298.591 us; speedup vs baseline: 1.1333x; 1.1333x over previous
//
#include <hip/hip_runtime.h>

#define NN 50000
#define NE 400000
#define DIN 32
#define DH  128
#define DOUT 16
#define NB  2
#define NBLK 49          // ceil(NN/1024)
#define NTILE (NE / 64)  // 6250

typedef _Float16 half8 __attribute__((ext_vector_type(8)));
typedef _Float16 half4 __attribute__((ext_vector_type(4)));
typedef float    f32x4 __attribute__((ext_vector_type(4)));

#define FENCE() asm volatile("s_waitcnt lgkmcnt(0)" ::: "memory")
#define MFMA16(a, b, c) __builtin_amdgcn_mfma_f32_16x16x32_f16((a), (b), (c), 0, 0, 0)

// ---------------------------------------------------------------------------
// Mega-prep kernel: weight fragments + dst histogram (round 11/12, verified).
// wf layout (chunks): [0, NB*12288) blocks | [+256) wout | [+512) win
__global__ void k_prep(const float* __restrict__ w1a, const float* __restrict__ w1b,
                       const float* __restrict__ w1c, const float* __restrict__ w2a,
                       const float* __restrict__ w2b, const float* __restrict__ wout,
                       const float* __restrict__ win, const int* __restrict__ dstI,
                       _Float16* __restrict__ wf, int* __restrict__ deg) {
    const int b = blockIdx.x, tid = threadIdx.x;
    if (b < (NB * 12288) / 256) {               // ---- block-weight frags
        int c = b * 256 + tid;
        int bb = c / 12288, r = c % 12288;
        int tt = r >> 9, rem = r & 511;
        const float* W; int t;
        if (tt < 8)       { W = w1a + (size_t)bb * 2 * DH * DH; t = tt; }
        else if (tt < 12) { W = w1b + (size_t)bb * DH * DH; t = tt - 8; }
        else if (tt < 16) { W = w1c + (size_t)bb * DH * DH; t = tt - 12; }
        else if (tt < 20) { W = w2a + (size_t)bb * DH * DH; t = tt - 16; }
        else              { W = w2b + (size_t)bb * DH * DH; t = tt - 20; }
        bool perm = (tt >= 12 && tt < 16);      // w1c only (in-lane phi)
        int n = rem >> 6, l = rem & 63;
        int col = n * 16 + (l & 15);
        half8 v;
#pragma unroll
        for (int j = 0; j < 8; ++j) {
            int row = perm ? ((2 * t + (j >> 2)) * 16 + (l >> 4) * 4 + (j & 3))
                           : (t * 32 + (l >> 4) * 8 + j);
            v[j] = (_Float16)W[(size_t)row * DH + col];
        }
        *(half8*)(wf + (size_t)c * 8) = v;
    } else if (b == 96) {                       // ---- wout frags (256 chunks)
        int c = tid;
        int t = c >> 6, l = c & 63;
        half8 v;
#pragma unroll
        for (int j = 0; j < 8; ++j)
            v[j] = (_Float16)wout[(size_t)(t * 32 + (l >> 4) * 8 + j) * DOUT + (l & 15)];
        *(half8*)(wf + (size_t)(NB * 12288 + c) * 8) = v;
    } else if (b < 99) {                        // ---- win frags (512 chunks, K=32)
        int c = (b - 97) * 256 + tid;
        int n = c >> 6, l = c & 63;
        half8 v;
#pragma unroll
        for (int j = 0; j < 8; ++j)
            v[j] = (_Float16)win[(size_t)((l >> 4) * 8 + j) * DH + n * 16 + (l & 15)];
        *(half8*)(wf + (size_t)(NB * 12288 + 256 + c) * 8) = v;
    } else {                                    // ---- dst histogram
        int e = (b - 99) * 256 + tid;
        if (e < NE) atomicAdd(&deg[dstI[e]], 1);
    }
}

// ---------------------------------------------------------------------------
// CSR sort by dst: 3-phase scan -> scatter
__global__ void __launch_bounds__(1024) k_scanA(const int* __restrict__ deg,
                                                int* __restrict__ bsum) {
    __shared__ int ws[16];
    int tid = threadIdx.x, wv = tid >> 6, l = tid & 63;
    int i = blockIdx.x * 1024 + tid;
    int v = (i < NN) ? deg[i] : 0;
#pragma unroll
    for (int off = 32; off; off >>= 1) v += __shfl_down(v, off);
    if (l == 0) ws[wv] = v;
    __syncthreads();
    if (tid == 0) {
        int s = 0;
#pragma unroll
        for (int k = 0; k < 16; ++k) s += ws[k];
        bsum[blockIdx.x] = s;
    }
}

__global__ void k_scanB(const int* __restrict__ bsum, int* __restrict__ boff) {
    int l = threadIdx.x;  // 64 threads
    int v = (l < NBLK) ? bsum[l] : 0;
    int s = v;
#pragma unroll
    for (int off = 1; off < 64; off <<= 1) {
        int t = __shfl_up(s, off);
        if (l >= off) s += t;
    }
    if (l < NBLK) boff[l] = s - v;
}

__global__ void __launch_bounds__(1024) k_scanC(const int* __restrict__ deg,
                                                const int* __restrict__ boff,
                                                int* __restrict__ cur) {
    __shared__ int ws[16];
    int tid = threadIdx.x, wv = tid >> 6, l = tid & 63;
    int i = blockIdx.x * 1024 + tid;
    int v = (i < NN) ? deg[i] : 0;
    int s = v;
#pragma unroll
    for (int off = 1; off < 64; off <<= 1) {
        int t = __shfl_up(s, off);
        if (l >= off) s += t;
    }
    if (l == 63) ws[wv] = s;
    __syncthreads();
    if (wv == 0) {
        int t = (l < 16) ? ws[l] : 0;
#pragma unroll
        for (int off = 1; off < 16; off <<= 1) {
            int u = __shfl_up(t, off);
            if (l >= off) t += u;
        }
        if (l < 16) ws[l] = t;
    }
    __syncthreads();
    int base = boff[blockIdx.x] + (wv ? ws[wv - 1] : 0);
    if (i < NN) cur[i] = base + s - v;
}

__global__ void k_scatter(const int* __restrict__ srcI, const int* __restrict__ dstI,
                          int* __restrict__ cur, int* __restrict__ eS,
                          int* __restrict__ eD) {
    int e = blockIdx.x * blockDim.x + threadIdx.x;
    if (e >= NE) return;
    int d = dstI[e];
    int p = atomicAdd(&cur[d], 1);
    eS[p] = srcI[e];
    eD[p] = d;
}

// ---------------------------------------------------------------------------
// Fused input proj + y precompute (block 0) + agg zeroing:
//   x = inputs @ win + bin  (MFMA, K=32; frag hand-off via LDS)
//   yj = x @ w1a[0:128], yi = x @ w1a[128:256] + b1a
//   agg[rows n0..n0+15] = 0   (exclusive row ownership; replaces memset)
__global__ void __launch_bounds__(256, 4) k_y0(
    const float* __restrict__ inp,
    const half8* __restrict__ winf, const float* __restrict__ bin,
    const half8* __restrict__ wfa, const float* __restrict__ b1a,
    _Float16* __restrict__ yj, _Float16* __restrict__ yi,
    float* __restrict__ agg) {
    __shared__ _Float16 sM[4][2048];
    const int tid = threadIdx.x, wv = tid >> 6, l = tid & 63;
    const int lm = l & 15, lk = l >> 4;
    const int n0 = (blockIdx.x * 4 + wv) * 16;
    if (n0 >= NN) return;
    int node = n0 + lm;
    if (node >= NN) node = NN - 1;

    // zero agg rows owned by this wave (stream-ordered before k_edge10)
    {
        float4 z4 = make_float4(0.f, 0.f, 0.f, 0.f);
#pragma unroll
        for (int r = 0; r < 4; ++r) {
            int nd = n0 + lk * 4 + r;
            if (nd < NN) {
                float4* q = (float4*)(agg + (size_t)nd * DH + lm * 8);
                q[0] = z4; q[1] = z4;
            }
        }
    }

    const f32x4 z = {0.f, 0.f, 0.f, 0.f};
    // ---- stage 1: x tile (K=32, one t)
    half8 a0;
    {
        const float* ip = inp + (size_t)node * DIN + lk * 8;
        float4 v0 = *(const float4*)ip;
        float4 v1 = *(const float4*)(ip + 4);
#pragma unroll
        for (int j = 0; j < 4; ++j) {
            a0[j]     = (_Float16)(&v0.x)[j];
            a0[4 + j] = (_Float16)(&v1.x)[j];
        }
    }
    f32x4 xacc[8];
#pragma unroll
    for (int n = 0; n < 8; ++n) xacc[n] = z;
#pragma unroll
    for (int n = 0; n < 8; ++n) xacc[n] = MFMA16(a0, winf[n * 64 + l], xacc[n]);

    // x (+bin) -> A-frag layout in wave-private LDS (verified ep_store map)
    _Float16* sm = sM[wv];
#pragma unroll
    for (int n = 0; n < 8; ++n) {
        float bi = bin[n * 16 + lm];
        int base = ((n >> 1) * 64 + ((n & 1) * 2 + (lm >> 3)) * 16 + lk * 4) * 8 +
                   (lm & 7);
#pragma unroll
        for (int j = 0; j < 4; ++j)
            sm[base + j * 8] = (_Float16)(xacc[n][j] + bi);
    }
    FENCE();

    // ---- stage 2: y GEMMs
    f32x4 aj[8], ai[8];
#pragma unroll
    for (int n = 0; n < 8; ++n) { aj[n] = z; ai[n] = z; }
#pragma unroll
    for (int t = 0; t < 4; ++t) {
        half8 a = *(const half8*)&sm[(t * 64 + l) * 8];
#pragma unroll
        for (int n = 0; n < 8; ++n) {
            aj[n] = MFMA16(a, wfa[(size_t)(t * 8 + n) * 64 + l], aj[n]);
            ai[n] = MFMA16(a, wfa[(size_t)((t + 4) * 8 + n) * 64 + l], ai[n]);
        }
    }
#pragma unroll
    for (int n = 0; n < 8; ++n) {
        float bi = b1a[n * 16 + lm];
#pragma unroll
        for (int r = 0; r < 4; ++r) {
            int nd = n0 + lk * 4 + r;
            if (nd < NN) {
                yj[(size_t)nd * DH + n * 16 + lm] = (_Float16)aj[n][r];
                yi[(size_t)nd * DH + n * 16 + lm] = (_Float16)(ai[n][r] + bi);
            }
        }
    }
}

// ---------------------------------------------------------------------------
// Edge MLP: round-12 verified config (93us/dispatch) — __launch_bounds__(256,3).
// BARRIER-FREE: wave owns 16 sorted edges x all 8 feat groups.
__global__ void __launch_bounds__(256, 3) k_edge10(
    const _Float16* __restrict__ yj, const _Float16* __restrict__ yi,
    const int* __restrict__ eS, const int* __restrict__ eD,
    const half8* __restrict__ wfb, const half8* __restrict__ wfc,
    const float* __restrict__ b1b,
    float* __restrict__ agg) {
    __shared__ _Float16 smAll[4][4096];   // 8KB/wave segsum B-region
    __shared__ int slotT[4][16];

    const int tid = threadIdx.x, wv = tid >> 6, l = tid & 63;
    const int lm = l & 15, lk = l >> 4;

    // bijective XCD-chunked tile swizzle (NTILE=6250: q=781, r=2)
    int bid = blockIdx.x;
    int xcd = bid & 7, idx = bid >> 3;
    int tile = (xcd < 2 ? xcd * 782 : 2 * 782 + (xcd - 2) * 781) + idx;
    const int ebase = tile * 64 + wv * 16;

    const int src = eS[ebase + lm];   // this lane's own edge
    const int dst = eD[ebase + lm];

    _Float16* sm = smAll[wv];
    // zero the k-slots 16..31 region once (edges only occupy 0..15)
    if (lk >= 2) {
        half8 zz;
#pragma unroll
        for (int j = 0; j < 8; ++j) zz[j] = (_Float16)0.f;
#pragma unroll
        for (int g = 0; g < 8; ++g) *(half8*)&sm[(g * 64 + l) * 8] = zz;
    }

    // run/slot machinery over this wave's 16 sorted dsts
    int dprev = __shfl(dst, (l & 48) | ((lm - 1) & 15));
    bool bit = (lm == 0) || (dst != dprev);
    unsigned mask16 = (unsigned)__ballot(bit) & 0xFFFFu;
    int slot_l = __popc(mask16 & ((2u << lm) - 1)) - 1;
    int nsl = __popc(mask16);
    if (l < 16 && bit) slotT[wv][slot_l] = dst;

    // b1b as f16 (tiny/zero values; within tolerance)
    half4 bb[8];
#pragma unroll
    for (int n = 0; n < 8; ++n) {
        float4 bf = *(const float4*)(b1b + n * 16 + lk * 4);
#pragma unroll
        for (int r = 0; r < 4; ++r) bb[n][r] = (_Float16)(&bf.x)[r];
    }

    const f32x4 z = {0.f, 0.f, 0.f, 0.f};
    f32x4 acc[8];
#pragma unroll
    for (int n = 0; n < 8; ++n) acc[n] = z;

    // ---- layer 2: K=128, B = relu(yj+yi) gathered per-lane
#pragma unroll
    for (int t = 0; t < 4; ++t) {
        half8 ya = *(const half8*)(yj + (size_t)src * DH + t * 32 + lk * 8);
        half8 yb = *(const half8*)(yi + (size_t)dst * DH + t * 32 + lk * 8);
        half8 m1;
#pragma unroll
        for (int j = 0; j < 8; ++j) {
            _Float16 v = ya[j] + yb[j];
            m1[j] = v > (_Float16)0.f ? v : (_Float16)0.f;
        }
#pragma unroll
        for (int n = 0; n < 8; ++n)
            acc[n] = MFMA16(wfb[(size_t)(t * 8 + n) * 64 + l], m1, acc[n]);
    }

    // ---- layer 3: K=128, B built in-lane via phi from layer-2 acc
    f32x4 ac3[8];
#pragma unroll
    for (int n = 0; n < 8; ++n) ac3[n] = z;
#pragma unroll
    for (int t = 0; t < 4; ++t) {
        half8 b3;
#pragma unroll
        for (int j = 0; j < 8; ++j) {
            int n2 = 2 * t + (j >> 2), r = j & 3;
            float v = acc[n2][r] + (float)bb[n2][r];
            b3[j] = (_Float16)fmaxf(v, 0.f);
        }
#pragma unroll
        for (int n = 0; n < 8; ++n)
            ac3[n] = MFMA16(wfc[(size_t)(t * 8 + n) * 64 + l], b3, ac3[n]);
    }

    // ---- m3 -> segsum B-layout (wave-private; b1c folded later in k_node)
#pragma unroll
    for (int n = 0; n < 8; ++n)
#pragma unroll
        for (int r = 0; r < 4; ++r)
            sm[(n * 64 + (lm >> 3) * 16 + lk * 4 + r) * 8 + (lm & 7)] =
                (_Float16)ac3[n][r];
    FENCE();   // covers sm writes + slotT writes (wave-private)

    // ---- MFMA segment-sum + sparse atomics (nsl <= 16 always)
    half8 ind;
#pragma unroll
    for (int e8 = 0; e8 < 8; ++e8) {
        int ks = lk * 8 + e8;
        int se = __shfl(slot_l, ks & 15);
        ind[e8] = (ks < 16 && se == lm) ? (_Float16)1.f : (_Float16)0.f;
    }
    int4 dv = *(const int4*)&slotT[wv][lk * 4];
#pragma unroll
    for (int g = 0; g < 8; ++g) {
        half8 bf = *(const half8*)&sm[(g * 64 + l) * 8];
        f32x4 p = MFMA16(ind, bf, z);
#pragma unroll
        for (int r = 0; r < 4; ++r) {
            int s0 = lk * 4 + r;
            if (s0 < nsl)
                unsafeAtomicAdd(agg + (size_t)(&dv.x)[r] * DH + g * 16 + lm, p[r]);
        }
    }
}

// ---------------------------------------------------------------------------
// Node MLP: x = relu((agg + deg*b1c)@w2a + b2a)@w2b + b2b.
// MODE 0: zero agg after reading (replaces memset), then fuse
//         y(next block) = x @ w1a_next (+b1a_next).
// MODE 1: fuse out = x @ wout + bout.
template <int MODE>
__global__ void __launch_bounds__(256, 3) k_node10(
    float* __restrict__ agg, const int* __restrict__ deg,
    const float* __restrict__ b1c,
    const half8* __restrict__ w2af, const half8* __restrict__ w2bf,
    const float* __restrict__ b2a, const float* __restrict__ b2b,
    const half8* __restrict__ wfaN, const float* __restrict__ b1aN,
    _Float16* __restrict__ yj, _Float16* __restrict__ yi,
    const half8* __restrict__ woutf, const float* __restrict__ bout,
    float* __restrict__ out) {
    __shared__ _Float16 sM[4][2048];
    const int tid = threadIdx.x, wv = tid >> 6, l = tid & 63;
    const int lm = l & 15, lk = l >> 4;
    const int n0 = (blockIdx.x * 4 + wv) * 16;
    if (n0 >= NN) return;
    int nodeA = n0 + lm;
    if (nodeA >= NN) nodeA = NN - 1;
    const float degf = (float)deg[nodeA];

    float b2ar[8], b2br[8];
#pragma unroll
    for (int n = 0; n < 8; ++n) {
        b2ar[n] = b2a[n * 16 + lm];
        b2br[n] = b2b[n * 16 + lm];
    }

    const f32x4 z = {0.f, 0.f, 0.f, 0.f};
    f32x4 acc[8];
#pragma unroll
    for (int n = 0; n < 8; ++n) acc[n] = z;

    for (int t = 0; t < 4; ++t) {
        float* ap = agg + (size_t)nodeA * DH + t * 32 + lk * 8;
        float4 v0 = *(const float4*)ap;
        float4 v1 = *(const float4*)(ap + 4);
        if (MODE == 0) {   // re-zero for next block (row exclusively owned)
            float4 z4 = make_float4(0.f, 0.f, 0.f, 0.f);
            *(float4*)ap = z4;
            *(float4*)(ap + 4) = z4;
        }
        float4 c0 = *(const float4*)(b1c + t * 32 + lk * 8);
        float4 c1 = *(const float4*)(b1c + t * 32 + lk * 8 + 4);
        half8 a;
#pragma unroll
        for (int j = 0; j < 4; ++j) {
            a[j]     = (_Float16)((&v0.x)[j] + degf * (&c0.x)[j]);
            a[4 + j] = (_Float16)((&v1.x)[j] + degf * (&c1.x)[j]);
        }
        const half8* wp = w2af + (size_t)t * 512 + l;
#pragma unroll
        for (int n = 0; n < 8; ++n) acc[n] = MFMA16(a, wp[n * 64], acc[n]);
    }
    _Float16* sm = sM[wv];
#pragma unroll
    for (int n = 0; n < 8; ++n) {
        int base = ((n >> 1) * 64 + ((n & 1) * 2 + (lm >> 3)) * 16 + lk * 4) * 8 +
                   (lm & 7);
#pragma unroll
        for (int j = 0; j < 4; ++j)
            sm[base + j * 8] = (_Float16)fmaxf(acc[n][j] + b2ar[n], 0.f);
    }
    FENCE();
#pragma unroll
    for (int n = 0; n < 8; ++n) acc[n] = z;
    for (int t = 0; t < 4; ++t) {
        half8 a = *(const half8*)&sm[(t * 64 + l) * 8];
        const half8* wp = w2bf + (size_t)t * 512 + l;
#pragma unroll
        for (int n = 0; n < 8; ++n) acc[n] = MFMA16(a, wp[n * 64], acc[n]);
    }
    // stage x (+b2b) into frag buffer for the follow-on GEMM(s)
    FENCE();   // prior frag reads complete before overwrite
#pragma unroll
    for (int n = 0; n < 8; ++n) {
        int base = ((n >> 1) * 64 + ((n & 1) * 2 + (lm >> 3)) * 16 + lk * 4) * 8 +
                   (lm & 7);
#pragma unroll
        for (int j = 0; j < 4; ++j)
            sm[base + j * 8] = (_Float16)(acc[n][j] + b2br[n]);
    }
    FENCE();

    if (MODE == 0) {
        // y(next) = x @ w1aN (j-half t0..3, i-half t4..7; +b1aN on i)
        f32x4 aj[8], ai[8];
#pragma unroll
        for (int n = 0; n < 8; ++n) { aj[n] = z; ai[n] = z; }
#pragma unroll
        for (int t = 0; t < 4; ++t) {
            half8 a = *(const half8*)&sm[(t * 64 + l) * 8];
#pragma unroll
            for (int n = 0; n < 8; ++n) {
                aj[n] = MFMA16(a, wfaN[(size_t)(t * 8 + n) * 64 + l], aj[n]);
                ai[n] = MFMA16(a, wfaN[(size_t)((t + 4) * 8 + n) * 64 + l], ai[n]);
            }
        }
#pragma unroll
        for (int n = 0; n < 8; ++n) {
            float bi = b1aN[n * 16 + lm];
#pragma unroll
            for (int r = 0; r < 4; ++r) {
                int nd = n0 + lk * 4 + r;
                if (nd < NN) {
                    yj[(size_t)nd * DH + n * 16 + lm] = (_Float16)aj[n][r];
                    yi[(size_t)nd * DH + n * 16 + lm] = (_Float16)(ai[n][r] + bi);
                }
            }
        }
    } else {
        f32x4 ao = z;
        for (int t = 0; t < 4; ++t) {
            half8 a = *(const half8*)&sm[(t * 64 + l) * 8];
            ao = MFMA16(a, woutf[t * 64 + l], ao);
        }
        float bo = bout[lm];
#pragma unroll
        for (int j = 0; j < 4; ++j) {
            int nd = n0 + lk * 4 + j;
            if (nd < NN) out[(size_t)nd * DOUT + lm] = ao[j] + bo;
        }
    }
}

// ---------------------------------------------------------------------------
extern "C" void kernel_launch(void* const* d_in, const int* in_sizes, int n_in,
                              void* d_out, int out_size, void* d_ws, size_t ws_size,
                              hipStream_t stream) {
    const float* inputs = (const float*)d_in[0];
    const int* eidx = (const int*)d_in[2];
    const int* srcI = eidx;
    const int* dstI = eidx + NE;
    const float* win  = (const float*)d_in[3];
    const float* bin_ = (const float*)d_in[4];
    const float* wout = (const float*)d_in[5];
    const float* bout = (const float*)d_in[6];
    const float* w1a = (const float*)d_in[7];
    const float* b1a = (const float*)d_in[8];
    const float* w1b = (const float*)d_in[9];
    const float* b1b = (const float*)d_in[10];
    const float* w1c = (const float*)d_in[11];
    const float* b1c = (const float*)d_in[12];
    const float* w2a = (const float*)d_in[13];
    const float* b2a = (const float*)d_in[14];
    const float* w2b = (const float*)d_in[15];
    const float* b2b = (const float*)d_in[16];

    char* p = (char*)d_ws;
    _Float16* yj = (_Float16*)p;    p += (size_t)NN * DH * 2;              // 12.8MB
    _Float16* yi = (_Float16*)p;    p += (size_t)NN * DH * 2;              // 12.8MB
    _Float16* wfAll = (_Float16*)p; p += ((size_t)NB * 12288 + 768) * 16;  // 405KB
    float* agg   = (float*)p;       p += (size_t)NN * DH * 4;              // 25.6MB
    int* deg     = (int*)p;         p += (size_t)NN * 4;
    int* cur     = (int*)p;         p += (size_t)NN * 4;
    int* bsum    = (int*)p;         p += 256;
    int* boff    = (int*)p;         p += 256;
    int* eSrt    = (int*)p;         p += (size_t)NE * 4;
    int* eDrt    = (int*)p;         p += (size_t)NE * 4;
    float* out   = (float*)d_out;

    const half8* wb0 = (const half8*)wfAll;
    const half8* wb1 = (const half8*)(wfAll + (size_t)12288 * 8);
    const half8* wfW = (const half8*)(wfAll + (size_t)NB * 12288 * 8);        // wout
    const half8* wfI = (const half8*)(wfAll + (size_t)(NB * 12288 + 256) * 8); // win

    hipMemsetAsync(deg, 0, (size_t)NN * 4, stream);
    k_prep<<<99 + (NE + 255) / 256, 256, 0, stream>>>(
        w1a, w1b, w1c, w2a, w2b, wout, win, dstI, wfAll, deg);
    k_scanA<<<NBLK, 1024, 0, stream>>>(deg, bsum);
    k_scanB<<<1, 64, 0, stream>>>(bsum, boff);
    k_scanC<<<NBLK, 1024, 0, stream>>>(deg, boff, cur);
    k_scatter<<<(NE + 255) / 256, 256, 0, stream>>>(srcI, dstI, cur, eSrt, eDrt);

    const int NWGN = (NN + 63) / 64;
    // block 0 (agg zeroed inside k_y0)
    k_y0<<<NWGN, 256, 0, stream>>>(inputs, wfI, bin_, wb0, b1a, yj, yi, agg);
    k_edge10<<<NTILE, 256, 0, stream>>>(yj, yi, eSrt, eDrt,
                                        wb0 + 4096, wb0 + 6144, b1b, agg);
    k_node10<0><<<NWGN, 256, 0, stream>>>(
        agg, deg, b1c, wb0 + 8192, wb0 + 10240, b2a, b2b,
        wb1, b1a + DH, yj, yi, nullptr, nullptr, nullptr);
    // block 1 (agg re-zeroed by k_node10<0>)
    k_edge10<<<NTILE, 256, 0, stream>>>(yj, yi, eSrt, eDrt,
                                        wb1 + 4096, wb1 + 6144, b1b + DH, agg);
    k_node10<1><<<NWGN, 256, 0, stream>>>(
        agg, deg, b1c + DH, wb1 + 8192, wb1 + 10240, b2a + DH, b2b + DH,
        nullptr, nullptr, nullptr, nullptr, wfW, bout, out);
}